// Round 1
// baseline (246.819 us; speedup 1.0000x reference)
//
#include <hip/hip_runtime.h>

#define NFFT    800
#define HOP     200
#define FREQ    401
#define NB      32
#define TLEN    480000
#define NFRAMES 2401   // (TLEN + 800 - NFFT)/HOP + 1
#define PAD     400

// Pass 1: per-frame windowed parity sums.
// eo[b*NFRAMES + f] = (sum_{n even} win[n]*xp[b,200f+n], sum_{n odd} ...)
// xp is edge-padded x (pad=400 each side), done via index clamp.
__global__ void frame_sums(const float* __restrict__ x,
                           const float* __restrict__ win,   // w_fwd_real row 0 == window
                           float2* __restrict__ eo) {
    const int blk = blockIdx.x;
    const int f = blk % NFRAMES;
    const int b = blk / NFRAMES;
    const float* xb = x + (size_t)b * TLEN;
    const int base = f * HOP - PAD;   // global t for n=0 (may be <0 or >=TLEN: edge clamp)
    float acc = 0.f;
    // stride 256 is even -> each thread's partial has fixed parity = tid&1
    for (int n = threadIdx.x; n < NFFT; n += 256) {
        int t = base + n;
        t = min(max(t, 0), TLEN - 1);
        acc += win[n] * xb[t];
    }
    __shared__ float lds[256];
    lds[threadIdx.x] = acc;
    __syncthreads();
    // parity-preserving tree reduction (all strides even, stop at 2)
    for (int s = 128; s >= 2; s >>= 1) {
        if (threadIdx.x < (unsigned)s) lds[threadIdx.x] += lds[threadIdx.x + s];
        __syncthreads();
    }
    if (threadIdx.x == 0) eo[blk] = make_float2(lds[0], lds[1]);
}

// Pass 2: out[b,t] = sum over overlapping frames f of
//   win[n]^2/2 * x[b,t] + win[n]/800 * (parity(p) ? O_f : E_f),  n = p - 200f, p = t+400
__global__ void synth(const float* __restrict__ x,
                      const float* __restrict__ win,
                      const float2* __restrict__ eo,
                      float* __restrict__ out) {
    const int i = blockIdx.x * blockDim.x + threadIdx.x;  // over NB*TLEN/4
    if (i >= NB * (TLEN / 4)) return;
    const int b  = i / (TLEN / 4);
    const int t4 = (i - b * (TLEN / 4)) * 4;
    const float4 xv = ((const float4*)(x + (size_t)b * TLEN))[t4 >> 2];
    const float2* eob = eo + b * NFRAMES;
    const float xs[4] = {xv.x, xv.y, xv.z, xv.w};
    float r[4];
#pragma unroll
    for (int j = 0; j < 4; ++j) {
        const int p = t4 + j + PAD;
        int f_hi = p / HOP;                     // frame covers p while 200f <= p
        if (f_hi > NFRAMES - 1) f_hi = NFRAMES - 1;
        const int f_lo = (p >= NFFT) ? (p - NFFT) / HOP + 1 : 0;  // need p-200f <= 799
        const bool odd = (p & 1) != 0;
        float acc = 0.f;
        for (int f = f_lo; f <= f_hi; ++f) {
            const int n = p - f * HOP;
            const float w = win[n];
            const float2 s2 = eob[f];
            const float s = odd ? s2.y : s2.x;
            acc += w * (0.5f * w * xs[j] + (1.0f / 800.0f) * s);
        }
        r[j] = acc;
    }
    ((float4*)(out + (size_t)b * TLEN))[t4 >> 2] = make_float4(r[0], r[1], r[2], r[3]);
}

extern "C" void kernel_launch(void* const* d_in, const int* in_sizes, int n_in,
                              void* d_out, int out_size, void* d_ws, size_t ws_size,
                              hipStream_t stream) {
    const float* x   = (const float*)d_in[0];
    const float* wfr = (const float*)d_in[1];   // (401, 800); row 0 = window
    float* out = (float*)d_out;
    float2* eo = (float2*)d_ws;                 // NB*NFRAMES float2 = 614,656 B

    frame_sums<<<dim3(NB * NFRAMES), dim3(256), 0, stream>>>(x, wfr, eo);

    const int total = NB * (TLEN / 4);
    synth<<<dim3((total + 255) / 256), dim3(256), 0, stream>>>(x, wfr, eo, out);
}

// Round 2
// 142.289 us; speedup vs baseline: 1.7346x; 1.7346x over previous
//
#include <hip/hip_runtime.h>

#define NFFT    800
#define HOP     200
#define NB      32
#define TLEN    480000
#define NFRAMES 2401
#define PAD     400

#define TW      4000            // output span per block (480000/4000 = 120 blocks/batch)
#define NBLK_T  (TLEN / TW)     // 120
#define NFRLOC  23              // frames touching a TW span: TW/HOP + 3
#define XLEN    5200            // 200*(NFRLOC-1) + 800

// One fused kernel: stage x + window in LDS, compute per-frame even/odd
// windowed sums (the analytic collapse of STFT->mag/phase->iSTFT is
//   y_f[n] = win[n]/800 * (400*win[n]*x_f[n] + P_f(parity(n)))
// where P_f(e/o) = sum over same-parity n' of win[n']*x_f[n']),
// then overlap-add synthesize directly from LDS.
__global__ __launch_bounds__(256) void stft_fused(const float* __restrict__ x,
                                                  const float* __restrict__ win,
                                                  float* __restrict__ out) {
    __shared__ float  xs[XLEN];
    __shared__ float  ws[NFFT];
    __shared__ float2 eo[NFRLOC];

    const int blk = blockIdx.x;
    const int b   = blk / NBLK_T;
    const int t0  = (blk - b * NBLK_T) * TW;
    const int fbase  = t0 / HOP - 1;       // first (possibly invalid) covering frame
    const int xstart = t0 - 600;           // = 200*fbase - 400
    const float* xb = x + (size_t)b * TLEN;

    // stage window (800 floats, float4)
    for (int i = threadIdx.x; i < NFFT / 4; i += 256)
        ((float4*)ws)[i] = ((const float4*)win)[i];
    // stage x with edge clamp (coalesced)
    for (int j = threadIdx.x; j < XLEN; j += 256) {
        int t = xstart + j;
        t = min(max(t, 0), TLEN - 1);
        xs[j] = xb[t];
    }
    __syncthreads();

    // per-wave frame sums: E_f, O_f (parity of n within the frame)
    const int wave = threadIdx.x >> 6;
    const int lane = threadIdx.x & 63;
    for (int li = wave; li < NFRLOC; li += 4) {
        const int f = fbase + li;
        float ae = 0.f, ao = 0.f;
        if (f >= 0 && f < NFRAMES) {
            const float4* xv4 = (const float4*)(xs + HOP * li);  // 800*li bytes: aligned
            const float4* wv4 = (const float4*)ws;
            for (int i = lane; i < NFFT / 4; i += 64) {
                const float4 v = xv4[i];
                const float4 w = wv4[i];
                ae += w.x * v.x + w.z * v.z;
                ao += w.y * v.y + w.w * v.w;
            }
        }
        // wave-uniform branch; butterfly over all 64 lanes
        for (int m = 1; m < 64; m <<= 1) {
            ae += __shfl_xor(ae, m);
            ao += __shfl_xor(ao, m);
        }
        if (lane == 0) eo[li] = make_float2(ae, ao);
    }
    __syncthreads();

    // synthesize TW outputs from LDS, float4 stores
    float4* outb4 = (float4*)(out + (size_t)b * TLEN + t0);
    const float4* xs4 = (const float4*)(xs + 600);   // x[t0] lives at xs[600]; 2400B aligned
    for (int j4 = threadIdx.x; j4 < TW / 4; j4 += 256) {
        const float4 xv = xs4[j4];
        const float xa[4] = {xv.x, xv.y, xv.z, xv.w};
        float r[4];
        const int pbase = t0 + 4 * j4 + PAD;
#pragma unroll
        for (int c = 0; c < 4; ++c) {
            const int p = pbase + c;
            int fhi = p / HOP;
            if (fhi > NFRAMES - 1) fhi = NFRAMES - 1;
            const int flo = (p >= NFFT) ? (p - NFFT) / HOP + 1 : 0;
            const bool odd = (p & 1) != 0;
            float acc = 0.f;
            for (int f = flo; f <= fhi; ++f) {
                const int n = p - HOP * f;
                const float w = ws[n];
                const float2 s2 = eo[f - fbase];
                acc += w * (0.5f * w * xa[c] + (1.0f / 800.0f) * (odd ? s2.y : s2.x));
            }
            r[c] = acc;
        }
        outb4[j4] = make_float4(r[0], r[1], r[2], r[3]);
    }
}

extern "C" void kernel_launch(void* const* d_in, const int* in_sizes, int n_in,
                              void* d_out, int out_size, void* d_ws, size_t ws_size,
                              hipStream_t stream) {
    const float* x   = (const float*)d_in[0];
    const float* wfr = (const float*)d_in[1];   // (401, 800); row 0 = hann window
    float* out = (float*)d_out;

    stft_fused<<<dim3(NB * NBLK_T), dim3(256), 0, stream>>>(x, wfr, out);
}

// Round 3
// 128.865 us; speedup vs baseline: 1.9153x; 1.1042x over previous
//
#include <hip/hip_runtime.h>
#include <math.h>

#define NFFT    800
#define HOP     200
#define NB      32
#define TLEN    480000
#define NFRAMES 2401
#define PAD     400

#define TW      4000            // output span per block
#define NBLK_T  (TLEN / TW)     // 120
#define NFRLOC  23              // frames touching a TW span
#define XLEN    5200            // staged x incl. 600-halo each side
#define NSEG    20              // 200-sample hop segments per block

// Analytic collapse of STFT->mag/phase->iSTFT (verified rounds 0-2):
//   out[p] = x[t]*0.5*sum_f w[n_f]^2 + (1/800)*sum_f w[n_f]*S_f(par(p))
// With w[n]=0.5-0.5cos(2pi n/800) and n_f = p-200f:
//   sum_f w^2 = 1.5 (4 valid frames), and
//   sum_f w[n_f]*S_f = 0.5*A - 0.5*R*cos(2pi p/800 - psi)
// where A,R,psi depend only on the 200-sample segment and parity of p.
__global__ __launch_bounds__(256) void stft_fused(const float* __restrict__ x,
                                                  const float* __restrict__ win,
                                                  float* __restrict__ out) {
    __shared__ __align__(16) float xs[XLEN];
    __shared__ __align__(16) float ws[NFFT];
    __shared__ float2 eo[NFRLOC];
    __shared__ float4 segc[2][NSEG];   // [parity][seg] = (A', R', psi, _)

    const int blk = blockIdx.x;
    const int b   = blk / NBLK_T;
    const int bt  = blk - b * NBLK_T;
    const int t0  = bt * TW;
    const int fbase  = t0 / HOP - 1;
    const int xstart = t0 - 600;
    const float* xb = x + (size_t)b * TLEN;

    // stage window + x (edge clamp), coalesced
    for (int i = threadIdx.x; i < NFFT / 4; i += 256)
        ((float4*)ws)[i] = ((const float4*)win)[i];
    for (int j = threadIdx.x; j < XLEN; j += 256) {
        int t = xstart + j;
        t = min(max(t, 0), TLEN - 1);
        xs[j] = xb[t];
    }
    __syncthreads();

    const int wave = threadIdx.x >> 6;
    const int lane = threadIdx.x & 63;

    // window fragment pinned in registers (read once, reused for all frames)
    const float4* wv4 = (const float4*)ws;
    const float4 w0 = wv4[lane];
    const float4 w1 = wv4[lane + 64];
    const float4 w2 = wv4[lane + 128];
    const float4 w3 = (lane < 8) ? wv4[lane + 192] : make_float4(0.f, 0.f, 0.f, 0.f);

    // per-frame even/odd windowed sums -> eo[li]
    for (int li = wave; li < NFRLOC; li += 4) {
        const int f = fbase + li;
        float ae = 0.f, ao = 0.f;
        if (f >= 0 && f < NFRAMES) {
            const float4* xv4 = (const float4*)(xs + HOP * li);  // 800B-aligned
            float4 v;
            v = xv4[lane];       ae += w0.x * v.x + w0.z * v.z;  ao += w0.y * v.y + w0.w * v.w;
            v = xv4[lane + 64];  ae += w1.x * v.x + w1.z * v.z;  ao += w1.y * v.y + w1.w * v.w;
            v = xv4[lane + 128]; ae += w2.x * v.x + w2.z * v.z;  ao += w2.y * v.y + w2.w * v.w;
            if (lane < 8) {
                v = xv4[lane + 192];
                ae += w3.x * v.x + w3.z * v.z;  ao += w3.y * v.y + w3.w * v.w;
            }
        }
        for (int m = 1; m < 64; m <<= 1) { ae += __shfl_xor(ae, m); ao += __shfl_xor(ao, m); }
        if (lane == 0) eo[li] = make_float2(ae, ao);
    }
    __syncthreads();

    const bool slow = (fbase < 0) || (fbase + NFRLOC - 1 > NFRAMES - 1);

    if (!slow) {
        // per-segment trig constants (40 threads)
        if (threadIdx.x < 2 * NSEG) {
            const int par = threadIdx.x & 1;
            const int s   = threadIdx.x >> 1;
            float A = 0.f, C = 0.f, D = 0.f;
#pragma unroll
            for (int k = 0; k < 4; ++k) {
                const int li = s + k;
                const int f  = fbase + li;
                const float2 v = eo[li];
                const float  S = par ? v.y : v.x;
                const int fm = f & 3;
                A += S;
                C += (fm == 0) ? S : ((fm == 2) ? -S : 0.f);
                D += (fm == 1) ? S : ((fm == 3) ? -S : 0.f);
            }
            segc[par][s] = make_float4(A * (1.0f / 1600.0f),
                                       sqrtf(C * C + D * D) * (1.0f / 1600.0f),
                                       atan2f(D, C), 0.f);
        }
        __syncthreads();

        float4* outb4 = (float4*)(out + (size_t)b * TLEN + t0);
        const float4* xs4 = (const float4*)(xs + 600);
        const float delta = 6.28318530717958647692f / 800.0f;
        for (int j4 = threadIdx.x; j4 < TW / 4; j4 += 256) {
            const float4 xv = xs4[j4];
            const int s = j4 / 50;                 // hop segment
            const float4 ce = segc[0][s];
            const float4 co = segc[1][s];
            const int pm0 = (400 + 4 * j4) % 800;  // p mod 800 (t0 % 800 == 0)
            const float xa[4] = {xv.x, xv.y, xv.z, xv.w};
            float r[4];
#pragma unroll
            for (int c = 0; c < 4; ++c) {
                const float4 cc = (c & 1) ? co : ce;
                const float ang = (float)(pm0 + c) * delta - cc.z;
                r[c] = 0.75f * xa[c] + cc.x - cc.y * __cosf(ang);
            }
            outb4[j4] = make_float4(r[0], r[1], r[2], r[3]);
        }
    } else {
        // boundary blocks (first/last per row): general per-sample loop
        float4* outb4 = (float4*)(out + (size_t)b * TLEN + t0);
        const float4* xs4 = (const float4*)(xs + 600);
        for (int j4 = threadIdx.x; j4 < TW / 4; j4 += 256) {
            const float4 xv = xs4[j4];
            const float xa[4] = {xv.x, xv.y, xv.z, xv.w};
            float r[4];
            const int pbase = t0 + 4 * j4 + PAD;
#pragma unroll
            for (int c = 0; c < 4; ++c) {
                const int p = pbase + c;
                int fhi = p / HOP;
                if (fhi > NFRAMES - 1) fhi = NFRAMES - 1;
                const int flo = (p >= NFFT) ? (p - NFFT) / HOP + 1 : 0;
                const bool odd = (p & 1) != 0;
                float acc = 0.f;
                for (int f = flo; f <= fhi; ++f) {
                    const int n = p - HOP * f;
                    const float w = ws[n];
                    const float2 s2 = eo[f - fbase];
                    acc += w * (0.5f * w * xa[c] + (1.0f / 800.0f) * (odd ? s2.y : s2.x));
                }
                r[c] = acc;
            }
            outb4[j4] = make_float4(r[0], r[1], r[2], r[3]);
        }
    }
}

extern "C" void kernel_launch(void* const* d_in, const int* in_sizes, int n_in,
                              void* d_out, int out_size, void* d_ws, size_t ws_size,
                              hipStream_t stream) {
    const float* x   = (const float*)d_in[0];
    const float* wfr = (const float*)d_in[1];   // (401, 800); row 0 = hann window
    float* out = (float*)d_out;

    stft_fused<<<dim3(NB * NBLK_T), dim3(256), 0, stream>>>(x, wfr, out);
}